// Round 7
// baseline (340.943 us; speedup 1.0000x reference)
//
#include <hip/hip_runtime.h>

#define B_   2
#define H_   16
#define G_   4
#define S_   2048
#define D_   128
#define I_   2048

#define BM   128
#define BN   64
#define TPB  512   // 8 waves x 16 q-rows
#define NIT  (I_ / BN)   // 32

#define LDA  40    // A-scratch row stride: 32 + 8 pad

// T2 XOR-swizzle: permute 8-elem (16B) groups within a row by row&7.
// Applied identically on write and read (both sides are register-staged).
#define KIDX(r,c) ((r)*128 + ((c) ^ (((r)&7)<<3)))   // Ks/Us: [64][128] f16, no pad
#define VIDX(d,c) ((d)*64  + ((c) ^ (((d)&7)<<3)))   // Vt:    [128][64] f16, no pad

static constexpr float SCALE = 0.08838834764831845f;  // 1/sqrt(128)

typedef __fp16   p2v __attribute__((ext_vector_type(2)));   // cvt_pkrtz result type
typedef _Float16 h8v __attribute__((ext_vector_type(8)));
typedef float    f4v __attribute__((ext_vector_type(4)));

__global__ __launch_bounds__(TPB, 4) void flashmlp_kernel(
    const float* __restrict__ Qg, const float* __restrict__ Kg,
    const float* __restrict__ Ug, const float* __restrict__ Vg,
    float* __restrict__ Og)
{
    // LDS: (2*64*128 + 128*64 + 128*40) f16 = 58368 B   (2 blocks/CU: 117 KB < 160 KB)
    __shared__ _Float16 Ks[BN * 128];
    __shared__ _Float16 Us[BN * 128];
    __shared__ _Float16 Vt[D_ * 64];    // Vt[d][i] (transposed V tile), swizzled
    __shared__ _Float16 As[BM * LDA];   // wave-private rows [wave*16, wave*16+16)

    // ---- block decode with XCD swizzle: xcd = bid&7 -> kv-head = xcd>>1
    const int bid   = blockIdx.x;
    const int xcd   = bid & 7;
    const int kh    = xcd >> 1;
    const int j     = ((bid >> 3) << 1) | (xcd & 1);   // 0..127 within head
    const int stile = j & 15;
    const int bg    = j >> 4;          // 0..7
    const int b     = bg >> 2;
    const int g     = bg & 3;
    const int h     = kh * G_ + g;

    const int tid  = threadIdx.x;
    const int wave = tid >> 6;         // 0..7
    const int lane = tid & 63;
    const int m16  = lane & 15;
    const int qq   = lane >> 4;        // 0..3

    const size_t qbase  = ((size_t)(b * H_ + h) * S_ + (size_t)stile * BM) * D_;
    const size_t kvbase = (size_t)kh * I_ * D_;

    // ---- Q fragments (A-operand), f32 -> f16 with SCALE folded in. 16 rows per wave.
    h8v qf[4];
    {
        const float* qp = Qg + qbase + (size_t)(wave * 16 + m16) * D_;
#pragma unroll
        for (int ks = 0; ks < 4; ++ks) {
            const float4 a = *(const float4*)(qp + ks * 32 + qq * 8);
            const float4 c = *(const float4*)(qp + ks * 32 + qq * 8 + 4);
            h8v v;
            p2v* v2 = (p2v*)&v;
            v2[0] = __builtin_amdgcn_cvt_pkrtz(a.x * SCALE, a.y * SCALE);
            v2[1] = __builtin_amdgcn_cvt_pkrtz(a.z * SCALE, a.w * SCALE);
            v2[2] = __builtin_amdgcn_cvt_pkrtz(c.x * SCALE, c.y * SCALE);
            v2[3] = __builtin_amdgcn_cvt_pkrtz(c.z * SCALE, c.w * SCALE);
            qf[ks] = v;
        }
    }

    f4v acc_o[8];
#pragma unroll
    for (int dt = 0; dt < 8; ++dt)
        acc_o[dt] = f4v{0.f, 0.f, 0.f, 0.f};

    const int sr = tid >> 3;          // K/U staging row 0..63 (8 threads/row)
    const int sc = (tid & 7) * 16;    // K/U staging col base
    const float* kbp = Kg + kvbase + (size_t)sr * D_ + sc;
    const float* ubp = Ug + kvbase + (size_t)sr * D_ + sc;

    // ---- T14 async-stage: K/U tile t+1 prefetched into regs during compute of t.
    float4 kpre[4], upre[4];
#pragma unroll
    for (int g4 = 0; g4 < 4; ++g4) {
        kpre[g4] = *(const float4*)(kbp + g4 * 4);
        upre[g4] = *(const float4*)(ubp + g4 * 4);
    }

    for (int it = 0; it < NIT; ++it) {
        const int i0 = it * BN;

        __syncthreads();  // previous iter's Ks/Us/Vt reads must complete before overwrite

        // ---- V loads for THIS tile: issue first so their latency hides under the
        // K/U cvt+ds_write work below. Thread owns (d, io): 8 i-elems of one d row.
        float vtmp[2][8];
#pragma unroll
        for (int p = 0; p < 2; ++p) {
            const int idx = p * TPB + tid;
            const int d   = idx & 127;
            const int io  = idx >> 7;   // 0..7
            const float* vp = Vg + kvbase + (size_t)(i0 + io * 8) * D_ + d;
#pragma unroll
            for (int jj = 0; jj < 8; ++jj)
                vtmp[p][jj] = vp[(size_t)jj * D_];
        }

        // ---- K/U: packed cvt + swizzled LDS write from the prefetched registers
        {
            h8v kb[2], ub[2];
            p2v* kb2 = (p2v*)kb;
            p2v* ub2 = (p2v*)ub;
#pragma unroll
            for (int g4 = 0; g4 < 4; ++g4) {
                kb2[2 * g4 + 0] = __builtin_amdgcn_cvt_pkrtz(kpre[g4].x, kpre[g4].y);
                kb2[2 * g4 + 1] = __builtin_amdgcn_cvt_pkrtz(kpre[g4].z, kpre[g4].w);
                ub2[2 * g4 + 0] = __builtin_amdgcn_cvt_pkrtz(upre[g4].x, upre[g4].y);
                ub2[2 * g4 + 1] = __builtin_amdgcn_cvt_pkrtz(upre[g4].z, upre[g4].w);
            }
#pragma unroll
            for (int w8 = 0; w8 < 2; ++w8) {
                *(h8v*)(&Ks[KIDX(sr, sc + w8 * 8)]) = kb[w8];
                *(h8v*)(&Us[KIDX(sr, sc + w8 * 8)]) = ub[w8];
            }
        }

        // ---- V: packed cvt + swizzled transposed write (one 16B chunk per thread per p)
#pragma unroll
        for (int p = 0; p < 2; ++p) {
            const int idx = p * TPB + tid;
            const int d   = idx & 127;
            const int io  = idx >> 7;
            h8v w;
            p2v* w2 = (p2v*)&w;
            w2[0] = __builtin_amdgcn_cvt_pkrtz(vtmp[p][0], vtmp[p][1]);
            w2[1] = __builtin_amdgcn_cvt_pkrtz(vtmp[p][2], vtmp[p][3]);
            w2[2] = __builtin_amdgcn_cvt_pkrtz(vtmp[p][4], vtmp[p][5]);
            w2[3] = __builtin_amdgcn_cvt_pkrtz(vtmp[p][6], vtmp[p][7]);
            *(h8v*)(&Vt[VIDX(d, io * 8)]) = w;
        }

        __syncthreads();

        // ---- issue K/U prefetch for tile t+1; completes during the MFMA phase.
        if (it + 1 < NIT) {
            const float* kp = kbp + (size_t)(it + 1) * BN * D_;
            const float* up = ubp + (size_t)(it + 1) * BN * D_;
#pragma unroll
            for (int g4 = 0; g4 < 4; ++g4) {
                kpre[g4] = *(const float4*)(kp + g4 * 4);
                upre[g4] = *(const float4*)(up + g4 * 4);
            }
        }

        // ---- M = Q K^T, N = Q U^T, gated per 16-col tile (16 rows per wave)
        _Float16 ag[4][4];
#pragma unroll
        for (int ct = 0; ct < 4; ++ct) {
            f4v am = f4v{0.f, 0.f, 0.f, 0.f};
            f4v an = am;
            __builtin_amdgcn_s_setprio(1);
#pragma unroll
            for (int ks = 0; ks < 4; ++ks) {
                const h8v kf = *(const h8v*)(&Ks[KIDX(ct * 16 + m16, ks * 32 + qq * 8)]);
                const h8v uf = *(const h8v*)(&Us[KIDX(ct * 16 + m16, ks * 32 + qq * 8)]);
                am = __builtin_amdgcn_mfma_f32_16x16x32_f16(qf[ks], kf, am, 0, 0, 0);
                an = __builtin_amdgcn_mfma_f32_16x16x32_f16(qf[ks], uf, an, 0, 0, 0);
            }
            __builtin_amdgcn_s_setprio(0);
            // gate: A = silu(M) * N   (SCALE already folded into Q)
#pragma unroll
            for (int r = 0; r < 4; ++r) {
                const float mv = am[r];
                const float nv = an[r];
                const float sg = __builtin_amdgcn_rcpf(1.f + __expf(-mv));
                ag[ct][r] = (_Float16)(mv * sg * nv);
            }
        }

        // ---- O += A V, two 32-col halves through wave-private As (no barriers:
        // each wave writes & reads only rows [wave*16, wave*16+16))
#pragma unroll
        for (int hh = 0; hh < 2; ++hh) {
#pragma unroll
            for (int c2 = 0; c2 < 2; ++c2) {
                const int ct = hh * 2 + c2;
#pragma unroll
                for (int r = 0; r < 4; ++r)
                    As[(wave * 16 + qq * 4 + r) * LDA + c2 * 16 + m16] = ag[ct][r];
            }
            // Vt fragments (full d-range for this 32-i half)
            h8v vfr[8];
#pragma unroll
            for (int dt = 0; dt < 8; ++dt)
                vfr[dt] = *(const h8v*)(&Vt[VIDX(dt * 16 + m16, hh * 32 + qq * 8)]);
            const h8v af = *(const h8v*)(&As[(wave * 16 + m16) * LDA + qq * 8]);
            __builtin_amdgcn_s_setprio(1);
#pragma unroll
            for (int dt = 0; dt < 8; ++dt)
                acc_o[dt] = __builtin_amdgcn_mfma_f32_16x16x32_f16(af, vfr[dt], acc_o[dt], 0, 0, 0);
            __builtin_amdgcn_s_setprio(0);
        }
    }

    // ---- epilogue: C-layout -> global fp32, 16 lanes write 64B runs per row
#pragma unroll
    for (int r = 0; r < 4; ++r) {
        const int row = stile * BM + wave * 16 + qq * 4 + r;
        float* op = Og + ((size_t)(b * H_ + h) * S_ + row) * D_;
#pragma unroll
        for (int dt = 0; dt < 8; ++dt)
            op[dt * 16 + m16] = acc_o[dt][r];
    }
}

extern "C" void kernel_launch(void* const* d_in, const int* in_sizes, int n_in,
                              void* d_out, int out_size, void* d_ws, size_t ws_size,
                              hipStream_t stream) {
    const float* Q = (const float*)d_in[0];
    const float* K = (const float*)d_in[1];
    const float* U = (const float*)d_in[2];
    const float* V = (const float*)d_in[3];
    float* out = (float*)d_out;

    const int grid = (S_ / BM) * B_ * H_;   // 512 blocks, 2/CU, 16 waves/CU
    flashmlp_kernel<<<dim3(grid), dim3(TPB), 0, stream>>>(Q, K, U, V, out);
}

// Round 8
// 317.079 us; speedup vs baseline: 1.0753x; 1.0753x over previous
//
#include <hip/hip_runtime.h>

#define B_   2
#define H_   16
#define G_   4
#define S_   2048
#define D_   128
#define I_   2048

#define BM   128
#define BN   64
#define TPB  512   // 8 waves x 16 q-rows
#define NIT  (I_ / BN)   // 32

#define LDA  40    // A-scratch row stride: 32 + 8 pad

// T2 XOR-swizzle: permute 8-elem (16B) groups within a row by row&7.
// Applied identically on write and read (both sides are register-staged).
#define KIDX(r,c) ((r)*128 + ((c) ^ (((r)&7)<<3)))   // Ks/Us: [64][128] f16, no pad
#define VIDX(d,c) ((d)*64  + ((c) ^ (((d)&7)<<3)))   // Vt:    [128][64] f16, no pad

static constexpr float SCALE = 0.08838834764831845f;  // 1/sqrt(128)

typedef __fp16   p2v __attribute__((ext_vector_type(2)));   // cvt_pkrtz result type
typedef _Float16 h8v __attribute__((ext_vector_type(8)));
typedef float    f4v __attribute__((ext_vector_type(4)));

__global__ __launch_bounds__(TPB, 2) void flashmlp_kernel(
    const float* __restrict__ Qg, const float* __restrict__ Kg,
    const float* __restrict__ Ug, const float* __restrict__ Vg,
    float* __restrict__ Og)
{
    // LDS: (2*64*128 + 128*64 + 128*40) f16 = 59392 B  (2 blocks/CU: 118.8 KB < 160 KB)
    __shared__ _Float16 Ks[BN * 128];
    __shared__ _Float16 Us[BN * 128];
    __shared__ _Float16 Vt[D_ * 64];    // Vt[d][i] (transposed V tile), swizzled
    __shared__ _Float16 As[BM * LDA];   // wave-private rows [wave*16, wave*16+16)

    // ---- block decode with XCD swizzle: xcd = bid&7 -> kv-head = xcd>>1
    const int bid   = blockIdx.x;
    const int xcd   = bid & 7;
    const int kh    = xcd >> 1;
    const int j     = ((bid >> 3) << 1) | (xcd & 1);   // 0..127 within head
    const int stile = j & 15;
    const int bg    = j >> 4;          // 0..7
    const int b     = bg >> 2;
    const int g     = bg & 3;
    const int h     = kh * G_ + g;

    const int tid  = threadIdx.x;
    const int wave = tid >> 6;         // 0..7
    const int lane = tid & 63;
    const int m16  = lane & 15;
    const int qq   = lane >> 4;        // 0..3

    const size_t qbase  = ((size_t)(b * H_ + h) * S_ + (size_t)stile * BM) * D_;
    const size_t kvbase = (size_t)kh * I_ * D_;

    // ---- Q fragments (A-operand), f32 -> f16 with SCALE folded in. 16 rows per wave.
    h8v qf[4];
    {
        const float* qp = Qg + qbase + (size_t)(wave * 16 + m16) * D_;
#pragma unroll
        for (int ks = 0; ks < 4; ++ks) {
            const float4 a = *(const float4*)(qp + ks * 32 + qq * 8);
            const float4 c = *(const float4*)(qp + ks * 32 + qq * 8 + 4);
            h8v v;
            p2v* v2 = (p2v*)&v;
            v2[0] = __builtin_amdgcn_cvt_pkrtz(a.x * SCALE, a.y * SCALE);
            v2[1] = __builtin_amdgcn_cvt_pkrtz(a.z * SCALE, a.w * SCALE);
            v2[2] = __builtin_amdgcn_cvt_pkrtz(c.x * SCALE, c.y * SCALE);
            v2[3] = __builtin_amdgcn_cvt_pkrtz(c.z * SCALE, c.w * SCALE);
            qf[ks] = v;
        }
    }

    f4v acc_o[8];
#pragma unroll
    for (int dt = 0; dt < 8; ++dt)
        acc_o[dt] = f4v{0.f, 0.f, 0.f, 0.f};

    // ---- staging split: threads 0-255 stage K, 256-511 stage U (halves per-thread
    // prefetch registers and cvt work vs staging both matrices per thread)
    const int tK = tid & 255;
    const int sr = tK >> 2;            // row 0..63
    const int sc = (tK & 3) * 32;      // col base
    const float* sbp = ((tid >> 8) ? Ug : Kg) + kvbase + (size_t)sr * D_ + sc;
    _Float16* Ss = (tid >> 8) ? Us : Ks;

    // V prefetch ownership: thread covers (d, io) pairs; 8 consecutive i per slot
    const int d0  = tid & 127;
    const int io0 = tid >> 7;          // 0..3  (p adds 4)

    // ---- T14 async-stage: K-or-U and V for tile t+1 live in regs during compute of t
    float4 spre[8];
    float  vpre[2][8];
#pragma unroll
    for (int g8 = 0; g8 < 8; ++g8)
        spre[g8] = *(const float4*)(sbp + g8 * 4);
#pragma unroll
    for (int p = 0; p < 2; ++p) {
        const int io = io0 + p * 4;
        const float* vp = Vg + kvbase + (size_t)(io * 8) * D_ + d0;
#pragma unroll
        for (int jj = 0; jj < 8; ++jj)
            vpre[p][jj] = vp[(size_t)jj * D_];
    }

    for (int it = 0; it < NIT; ++it) {
        __syncthreads();  // previous iter's Ks/Us/Vt reads must complete before overwrite

        // ---- K-or-U: packed cvt + swizzled LDS write from prefetched registers
        {
            h8v sb[4];
            p2v* sb2 = (p2v*)sb;
#pragma unroll
            for (int g8 = 0; g8 < 8; ++g8) {
                sb2[2 * g8 + 0] = __builtin_amdgcn_cvt_pkrtz(spre[g8].x, spre[g8].y);
                sb2[2 * g8 + 1] = __builtin_amdgcn_cvt_pkrtz(spre[g8].z, spre[g8].w);
            }
#pragma unroll
            for (int w8 = 0; w8 < 4; ++w8)
                *(h8v*)(&Ss[KIDX(sr, sc + w8 * 8)]) = sb[w8];
        }

        // ---- V: packed cvt + swizzled transposed write
#pragma unroll
        for (int p = 0; p < 2; ++p) {
            const int io = io0 + p * 4;
            h8v w;
            p2v* w2 = (p2v*)&w;
            w2[0] = __builtin_amdgcn_cvt_pkrtz(vpre[p][0], vpre[p][1]);
            w2[1] = __builtin_amdgcn_cvt_pkrtz(vpre[p][2], vpre[p][3]);
            w2[2] = __builtin_amdgcn_cvt_pkrtz(vpre[p][4], vpre[p][5]);
            w2[3] = __builtin_amdgcn_cvt_pkrtz(vpre[p][6], vpre[p][7]);
            *(h8v*)(&Vt[VIDX(d0, io * 8)]) = w;
        }

        __syncthreads();

        // ---- issue K/U/V prefetch for tile t+1; completes during the MFMA phase.
        if (it + 1 < NIT) {
            const float* sp = sbp + (size_t)(it + 1) * BN * D_;
#pragma unroll
            for (int g8 = 0; g8 < 8; ++g8)
                spre[g8] = *(const float4*)(sp + g8 * 4);
#pragma unroll
            for (int p = 0; p < 2; ++p) {
                const int io = io0 + p * 4;
                const float* vp = Vg + kvbase + (size_t)((it + 1) * BN + io * 8) * D_ + d0;
#pragma unroll
                for (int jj = 0; jj < 8; ++jj)
                    vpre[p][jj] = vp[(size_t)jj * D_];
            }
        }

        // ---- M = Q K^T, N = Q U^T, gated per 16-col tile (16 rows per wave)
        _Float16 ag[4][4];
#pragma unroll
        for (int ct = 0; ct < 4; ++ct) {
            f4v am = f4v{0.f, 0.f, 0.f, 0.f};
            f4v an = am;
            __builtin_amdgcn_s_setprio(1);
#pragma unroll
            for (int ks = 0; ks < 4; ++ks) {
                const h8v kf = *(const h8v*)(&Ks[KIDX(ct * 16 + m16, ks * 32 + qq * 8)]);
                const h8v uf = *(const h8v*)(&Us[KIDX(ct * 16 + m16, ks * 32 + qq * 8)]);
                am = __builtin_amdgcn_mfma_f32_16x16x32_f16(qf[ks], kf, am, 0, 0, 0);
                an = __builtin_amdgcn_mfma_f32_16x16x32_f16(qf[ks], uf, an, 0, 0, 0);
            }
            __builtin_amdgcn_s_setprio(0);
            // gate: A = silu(M) * N   (SCALE already folded into Q)
#pragma unroll
            for (int r = 0; r < 4; ++r) {
                const float mv = am[r];
                const float nv = an[r];
                const float sg = __builtin_amdgcn_rcpf(1.f + __expf(-mv));
                ag[ct][r] = (_Float16)(mv * sg * nv);
            }
        }

        // ---- O += A V, two 32-col halves through wave-private As (no barriers:
        // each wave writes & reads only rows [wave*16, wave*16+16))
#pragma unroll
        for (int hh = 0; hh < 2; ++hh) {
#pragma unroll
            for (int c2 = 0; c2 < 2; ++c2) {
                const int ct = hh * 2 + c2;
#pragma unroll
                for (int r = 0; r < 4; ++r)
                    As[(wave * 16 + qq * 4 + r) * LDA + c2 * 16 + m16] = ag[ct][r];
            }
            h8v vfr[8];
#pragma unroll
            for (int dt = 0; dt < 8; ++dt)
                vfr[dt] = *(const h8v*)(&Vt[VIDX(dt * 16 + m16, hh * 32 + qq * 8)]);
            const h8v af = *(const h8v*)(&As[(wave * 16 + m16) * LDA + qq * 8]);
            __builtin_amdgcn_s_setprio(1);
#pragma unroll
            for (int dt = 0; dt < 8; ++dt)
                acc_o[dt] = __builtin_amdgcn_mfma_f32_16x16x32_f16(af, vfr[dt], acc_o[dt], 0, 0, 0);
            __builtin_amdgcn_s_setprio(0);
        }
    }

    // ---- epilogue: C-layout -> global fp32, 16 lanes write 64B runs per row
#pragma unroll
    for (int r = 0; r < 4; ++r) {
        const int row = stile * BM + wave * 16 + qq * 4 + r;
        float* op = Og + ((size_t)(b * H_ + h) * S_ + row) * D_;
#pragma unroll
        for (int dt = 0; dt < 8; ++dt)
            op[dt * 16 + m16] = acc_o[dt][r];
    }
}

extern "C" void kernel_launch(void* const* d_in, const int* in_sizes, int n_in,
                              void* d_out, int out_size, void* d_ws, size_t ws_size,
                              hipStream_t stream) {
    const float* Q = (const float*)d_in[0];
    const float* K = (const float*)d_in[1];
    const float* U = (const float*)d_in[2];
    const float* V = (const float*)d_in[3];
    float* out = (float*)d_out;

    const int grid = (S_ / BM) * B_ * H_;   // 512 blocks, 2/CU, 16 waves/CU
    flashmlp_kernel<<<dim3(grid), dim3(TPB), 0, stream>>>(Q, K, U, V, out);
}

// Round 9
// 208.396 us; speedup vs baseline: 1.6360x; 1.5215x over previous
//
#include <hip/hip_runtime.h>

#define B_   2
#define H_   16
#define G_   4
#define S_   2048
#define D_   128
#define I_   2048

#define BM   256
#define BN   64
#define TPB  512   // 8 waves x 32 q-rows (R3 per-wave geometry)
#define NIT  (I_ / BN)   // 32

#define LDA  40    // A-scratch row stride: 32 + 8 pad

#define KUSZ (BN * 128)   // one K or U buffer (f16 elems)
#define VSZ  (D_ * 64)    // one Vt buffer

// T2 XOR-swizzle: permute 8-elem (16B) groups within a row by row&7.
// Applied identically on write and read (both sides are register-staged).
#define KIDX(r,c) ((r)*128 + ((c) ^ (((r)&7)<<3)))   // Ks/Us: [64][128] f16, no pad
#define VIDX(d,c) ((d)*64  + ((c) ^ (((d)&7)<<3)))   // Vt:    [128][64] f16, no pad

static constexpr float SCALE = 0.08838834764831845f;  // 1/sqrt(128)

typedef __fp16   p2v __attribute__((ext_vector_type(2)));   // cvt_pkrtz result type
typedef _Float16 h8v __attribute__((ext_vector_type(8)));
typedef float    f4v __attribute__((ext_vector_type(4)));

__global__ __launch_bounds__(TPB, 2) void flashmlp_kernel(
    const float* __restrict__ Qg, const float* __restrict__ Kg,
    const float* __restrict__ Ug, const float* __restrict__ Vg,
    float* __restrict__ Og)
{
    // LDS: dbuf K/U/V + As = (2*8192*3 + 256*40) f16 = 59392 f16 = 118784 B (1 block/CU)
    __shared__ _Float16 Ks[2 * KUSZ];
    __shared__ _Float16 Us[2 * KUSZ];
    __shared__ _Float16 Vt[2 * VSZ];    // Vt[d][i] (transposed V tile), swizzled
    __shared__ _Float16 As[BM * LDA];   // wave-private rows [wave*32, wave*32+32)

    // ---- block decode with XCD swizzle: xcd = bid&7 -> kv-head = xcd>>1
    // grid 256 = 8 XCDs x 32; per head: 64 blocks (8 stiles x 8 bg) on 2 XCDs
    const int bid   = blockIdx.x;
    const int xcd   = bid & 7;
    const int kh    = xcd >> 1;
    const int j     = ((bid >> 3) << 1) | (xcd & 1);   // 0..63 within head
    const int stile = j & 7;           // 8 stiles of 256 rows
    const int bg    = j >> 3;          // 0..7
    const int b     = bg >> 2;
    const int g     = bg & 3;
    const int h     = kh * G_ + g;

    const int tid  = threadIdx.x;
    const int wave = tid >> 6;         // 0..7
    const int lane = tid & 63;
    const int m16  = lane & 15;
    const int qq   = lane >> 4;        // 0..3

    const size_t qbase  = ((size_t)(b * H_ + h) * S_ + (size_t)stile * BM) * D_;
    const size_t kvbase = (size_t)kh * I_ * D_;

    // ---- Q fragments (A-operand), f32 -> f16 with SCALE folded in. 32 rows per wave.
    h8v qf[2][4];
#pragma unroll
    for (int rt = 0; rt < 2; ++rt) {
        const float* qp = Qg + qbase + (size_t)(wave * 32 + rt * 16 + m16) * D_;
#pragma unroll
        for (int ks = 0; ks < 4; ++ks) {
            const float4 a = *(const float4*)(qp + ks * 32 + qq * 8);
            const float4 c = *(const float4*)(qp + ks * 32 + qq * 8 + 4);
            h8v v;
            p2v* v2 = (p2v*)&v;
            v2[0] = __builtin_amdgcn_cvt_pkrtz(a.x * SCALE, a.y * SCALE);
            v2[1] = __builtin_amdgcn_cvt_pkrtz(a.z * SCALE, a.w * SCALE);
            v2[2] = __builtin_amdgcn_cvt_pkrtz(c.x * SCALE, c.y * SCALE);
            v2[3] = __builtin_amdgcn_cvt_pkrtz(c.z * SCALE, c.w * SCALE);
            qf[rt][ks] = v;
        }
    }

    f4v acc_o[2][8];
#pragma unroll
    for (int rt = 0; rt < 2; ++rt)
#pragma unroll
        for (int dt = 0; dt < 8; ++dt)
            acc_o[rt][dt] = f4v{0.f, 0.f, 0.f, 0.f};

    // ---- staging ownership (512 threads stage once per CU):
    // K/U: thread -> (row sr, 16-col slice sc); V: thread -> (col d0, 16-i slice io4)
    const int sr  = tid >> 3;          // 0..63
    const int sc  = (tid & 7) * 16;    // 0,16,...,112
    const int d0  = tid & 127;
    const int io4 = (tid >> 7) * 16;   // 0,16,32,48
    const float* kbp = Kg + kvbase + (size_t)sr * D_ + sc;
    const float* ubp = Ug + kvbase + (size_t)sr * D_ + sc;

    float4 kpre[4], upre[4];
    float  vpre[16];

    // ---- prologue: load tile 0, cvt, write into buf 0
#pragma unroll
    for (int g4 = 0; g4 < 4; ++g4) {
        kpre[g4] = *(const float4*)(kbp + g4 * 4);
        upre[g4] = *(const float4*)(ubp + g4 * 4);
    }
#pragma unroll
    for (int jj = 0; jj < 16; ++jj)
        vpre[jj] = Vg[kvbase + (size_t)(io4 + jj) * D_ + d0];
    {
        h8v kb[2], ub[2], vb[2];
        p2v* kb2 = (p2v*)kb; p2v* ub2 = (p2v*)ub; p2v* vb2 = (p2v*)vb;
#pragma unroll
        for (int g4 = 0; g4 < 4; ++g4) {
            kb2[2 * g4 + 0] = __builtin_amdgcn_cvt_pkrtz(kpre[g4].x, kpre[g4].y);
            kb2[2 * g4 + 1] = __builtin_amdgcn_cvt_pkrtz(kpre[g4].z, kpre[g4].w);
            ub2[2 * g4 + 0] = __builtin_amdgcn_cvt_pkrtz(upre[g4].x, upre[g4].y);
            ub2[2 * g4 + 1] = __builtin_amdgcn_cvt_pkrtz(upre[g4].z, upre[g4].w);
        }
#pragma unroll
        for (int jj = 0; jj < 8; ++jj)
            vb2[jj] = __builtin_amdgcn_cvt_pkrtz(vpre[2 * jj], vpre[2 * jj + 1]);
        *(h8v*)(&Ks[KIDX(sr, sc + 0)]) = kb[0];
        *(h8v*)(&Ks[KIDX(sr, sc + 8)]) = kb[1];
        *(h8v*)(&Us[KIDX(sr, sc + 0)]) = ub[0];
        *(h8v*)(&Us[KIDX(sr, sc + 8)]) = ub[1];
        *(h8v*)(&Vt[VIDX(d0, io4 + 0)]) = vb[0];
        *(h8v*)(&Vt[VIDX(d0, io4 + 8)]) = vb[1];
    }
    __syncthreads();

    for (int it = 0; it < NIT; ++it) {
        const int cur = it & 1;
        const _Float16* ksb = Ks + cur * KUSZ;
        const _Float16* usb = Us + cur * KUSZ;
        const _Float16* vtb = Vt + cur * VSZ;

        // ---- 1) issue global loads for tile t+1 (stay in flight across QK phase)
        const bool more = (it + 1 < NIT);
        if (more) {
            const float* kp = kbp + (size_t)(it + 1) * BN * D_;
            const float* up = ubp + (size_t)(it + 1) * BN * D_;
#pragma unroll
            for (int g4 = 0; g4 < 4; ++g4) {
                kpre[g4] = *(const float4*)(kp + g4 * 4);
                upre[g4] = *(const float4*)(up + g4 * 4);
            }
            const float* vp = Vg + kvbase + (size_t)((it + 1) * BN + io4) * D_ + d0;
#pragma unroll
            for (int jj = 0; jj < 16; ++jj)
                vpre[jj] = vp[(size_t)jj * D_];
        }

        // ---- 2) M = Q K^T, N = Q U^T, gated per 16-col tile (reads buf[cur])
        _Float16 ag[2][4][4];
#pragma unroll
        for (int ct = 0; ct < 4; ++ct) {
            f4v am[2], an[2];
            am[0] = f4v{0.f, 0.f, 0.f, 0.f}; am[1] = am[0];
            an[0] = am[0]; an[1] = am[0];
            __builtin_amdgcn_s_setprio(1);
#pragma unroll
            for (int ks = 0; ks < 4; ++ks) {
                const h8v kf = *(const h8v*)(&ksb[KIDX(ct * 16 + m16, ks * 32 + qq * 8)]);
                const h8v uf = *(const h8v*)(&usb[KIDX(ct * 16 + m16, ks * 32 + qq * 8)]);
                am[0] = __builtin_amdgcn_mfma_f32_16x16x32_f16(qf[0][ks], kf, am[0], 0, 0, 0);
                am[1] = __builtin_amdgcn_mfma_f32_16x16x32_f16(qf[1][ks], kf, am[1], 0, 0, 0);
                an[0] = __builtin_amdgcn_mfma_f32_16x16x32_f16(qf[0][ks], uf, an[0], 0, 0, 0);
                an[1] = __builtin_amdgcn_mfma_f32_16x16x32_f16(qf[1][ks], uf, an[1], 0, 0, 0);
            }
            __builtin_amdgcn_s_setprio(0);
#pragma unroll
            for (int rt = 0; rt < 2; ++rt)
#pragma unroll
                for (int r = 0; r < 4; ++r) {
                    const float mv = am[rt][r];
                    const float nv = an[rt][r];
                    const float sg = __builtin_amdgcn_rcpf(1.f + __expf(-mv));
                    ag[rt][ct][r] = (_Float16)(mv * sg * nv);
                }
        }

        // ---- 3) cvt + ds_write tile t+1 into buf[cur^1] (overlaps with PV below;
        // no barrier needed: other buffer, and buf[cur^1] readers synced at iter end)
        if (more) {
            _Float16* ksn = Ks + (cur ^ 1) * KUSZ;
            _Float16* usn = Us + (cur ^ 1) * KUSZ;
            _Float16* vtn = Vt + (cur ^ 1) * VSZ;
            h8v kb[2], ub[2], vb[2];
            p2v* kb2 = (p2v*)kb; p2v* ub2 = (p2v*)ub; p2v* vb2 = (p2v*)vb;
#pragma unroll
            for (int g4 = 0; g4 < 4; ++g4) {
                kb2[2 * g4 + 0] = __builtin_amdgcn_cvt_pkrtz(kpre[g4].x, kpre[g4].y);
                kb2[2 * g4 + 1] = __builtin_amdgcn_cvt_pkrtz(kpre[g4].z, kpre[g4].w);
                ub2[2 * g4 + 0] = __builtin_amdgcn_cvt_pkrtz(upre[g4].x, upre[g4].y);
                ub2[2 * g4 + 1] = __builtin_amdgcn_cvt_pkrtz(upre[g4].z, upre[g4].w);
            }
#pragma unroll
            for (int jj = 0; jj < 8; ++jj)
                vb2[jj] = __builtin_amdgcn_cvt_pkrtz(vpre[2 * jj], vpre[2 * jj + 1]);
            *(h8v*)(&ksn[KIDX(sr, sc + 0)]) = kb[0];
            *(h8v*)(&ksn[KIDX(sr, sc + 8)]) = kb[1];
            *(h8v*)(&usn[KIDX(sr, sc + 0)]) = ub[0];
            *(h8v*)(&usn[KIDX(sr, sc + 8)]) = ub[1];
            *(h8v*)(&vtn[VIDX(d0, io4 + 0)]) = vb[0];
            *(h8v*)(&vtn[VIDX(d0, io4 + 8)]) = vb[1];
        }

        // ---- 4) O += A V, two 32-col halves through wave-private As (no barriers:
        // each wave writes & reads only rows [wave*32, wave*32+32))
#pragma unroll
        for (int hh = 0; hh < 2; ++hh) {
#pragma unroll
            for (int c2 = 0; c2 < 2; ++c2) {
                const int ct = hh * 2 + c2;
#pragma unroll
                for (int rt = 0; rt < 2; ++rt)
#pragma unroll
                    for (int r = 0; r < 4; ++r)
                        As[(wave * 32 + rt * 16 + qq * 4 + r) * LDA + c2 * 16 + m16] = ag[rt][ct][r];
            }
            h8v vfr[8];
#pragma unroll
            for (int dt = 0; dt < 8; ++dt)
                vfr[dt] = *(const h8v*)(&vtb[VIDX(dt * 16 + m16, hh * 32 + qq * 8)]);
#pragma unroll
            for (int rt = 0; rt < 2; ++rt) {
                const h8v af = *(const h8v*)(&As[(wave * 32 + rt * 16 + m16) * LDA + qq * 8]);
                __builtin_amdgcn_s_setprio(1);
#pragma unroll
                for (int dt = 0; dt < 8; ++dt)
                    acc_o[rt][dt] = __builtin_amdgcn_mfma_f32_16x16x32_f16(af, vfr[dt], acc_o[rt][dt], 0, 0, 0);
                __builtin_amdgcn_s_setprio(0);
            }
        }

        // ---- 5) single barrier: buf[cur^1] writes visible; buf[cur] reads done
        __syncthreads();
    }

    // ---- epilogue: C-layout -> global fp32, 16 lanes write 64B runs per row
#pragma unroll
    for (int rt = 0; rt < 2; ++rt) {
#pragma unroll
        for (int r = 0; r < 4; ++r) {
            const int row = stile * BM + wave * 32 + rt * 16 + qq * 4 + r;
            float* op = Og + ((size_t)(b * H_ + h) * S_ + row) * D_;
#pragma unroll
            for (int dt = 0; dt < 8; ++dt)
                op[dt * 16 + m16] = acc_o[rt][dt][r];
        }
    }
}

extern "C" void kernel_launch(void* const* d_in, const int* in_sizes, int n_in,
                              void* d_out, int out_size, void* d_ws, size_t ws_size,
                              hipStream_t stream) {
    const float* Q = (const float*)d_in[0];
    const float* K = (const float*)d_in[1];
    const float* U = (const float*)d_in[2];
    const float* V = (const float*)d_in[3];
    float* out = (float*)d_out;

    const int grid = (S_ / BM) * B_ * H_;   // 8 * 32 = 256 blocks, 1/CU
    flashmlp_kernel<<<dim3(grid), dim3(TPB), 0, stream>>>(Q, K, U, V, out);
}

// Round 12
// 200.258 us; speedup vs baseline: 1.7025x; 1.0406x over previous
//
#include <hip/hip_runtime.h>

#define B_   2
#define H_   16
#define G_   4
#define S_   2048
#define D_   128
#define I_   2048

#define BM   256
#define BN   64
#define TPB  512   // 8 waves x 32 q-rows
#define NIT  (I_ / BN)   // 32

#define KUSZ (BN * 128)   // one K or U buffer (f16 elems)
#define VSZ  (D_ * 64)    // one Vt buffer

// T2 XOR-swizzle on 8-elem (16B) granules by row&7; every LDS access is exactly
// one granule, so writes and reads stay 16B-aligned.
#define KIDX(r,c) ((r)*128 + ((c) ^ (((r)&7)<<3)))   // Ks/Us: [64][128] f16
#define VIDX(d,c) ((d)*64  + ((c) ^ (((d)&7)<<3)))   // Vt:    [128][64] f16

static constexpr float SCALE = 0.08838834764831845f;  // 1/sqrt(128)

typedef __fp16   p2v  __attribute__((ext_vector_type(2)));
typedef _Float16 h8v  __attribute__((ext_vector_type(8)));
typedef float    f4v  __attribute__((ext_vector_type(4)));
typedef float    f16v __attribute__((ext_vector_type(16)));
typedef int      i4v  __attribute__((ext_vector_type(4)));

__device__ __forceinline__ int pkf16(float a, float b) {
    p2v t = __builtin_amdgcn_cvt_pkrtz(a, b);
    int r; __builtin_memcpy(&r, &t, 4); return r;
}

__global__ __launch_bounds__(TPB, 2) void flashmlp_kernel(
    const float* __restrict__ Qg, const float* __restrict__ Kg,
    const float* __restrict__ Ug, const float* __restrict__ Vg,
    float* __restrict__ Og)
{
    // LDS: dbuf K/U/V = 2*(16+16+16) KB = 96 KB, no As buffer (1 block/CU)
    __shared__ _Float16 Ks[2 * KUSZ];
    __shared__ _Float16 Us[2 * KUSZ];
    __shared__ _Float16 Vt[2 * VSZ];    // Vt[d][i] (transposed V tile), swizzled

    // ---- block decode with XCD swizzle: xcd = bid&7 -> kv-head = xcd>>1
    const int bid   = blockIdx.x;
    const int xcd   = bid & 7;
    const int kh    = xcd >> 1;
    const int j     = ((bid >> 3) << 1) | (xcd & 1);   // 0..63 within head
    const int stile = j & 7;           // 8 stiles of 256 rows
    const int bg    = j >> 3;          // 0..7
    const int b     = bg >> 2;
    const int g     = bg & 3;
    const int h     = kh * G_ + g;

    const int tid  = threadIdx.x;
    const int wave = tid >> 6;         // 0..7
    const int lane = tid & 63;
    const int l31  = lane & 31;
    const int hl   = lane >> 5;        // 0..1 (lane half)

    const size_t qbase  = ((size_t)(b * H_ + h) * S_ + (size_t)stile * BM) * D_;
    const size_t kvbase = (size_t)kh * I_ * D_;

    // ---- Q fragments as the 32x32x16 B-operand: lane (q=l31) holds Q[q][ks*16+hl*8+j],
    // SCALE folded in. qf[8] = 32 VGPR.
    h8v qf[8];
    {
        const float* qp = Qg + qbase + (size_t)(wave * 32 + l31) * D_;
#pragma unroll
        for (int ks = 0; ks < 8; ++ks) {
            const float4 a = *(const float4*)(qp + ks * 16 + hl * 8);
            const float4 c = *(const float4*)(qp + ks * 16 + hl * 8 + 4);
            h8v v;
            p2v* v2 = (p2v*)&v;
            v2[0] = __builtin_amdgcn_cvt_pkrtz(a.x * SCALE, a.y * SCALE);
            v2[1] = __builtin_amdgcn_cvt_pkrtz(a.z * SCALE, a.w * SCALE);
            v2[2] = __builtin_amdgcn_cvt_pkrtz(c.x * SCALE, c.y * SCALE);
            v2[3] = __builtin_amdgcn_cvt_pkrtz(c.z * SCALE, c.w * SCALE);
            qf[ks] = v;
        }
    }

    // acc_o[dt]: O^T tile (32d x 32q): lane col q=l31, row d = dt*32+(reg&3)+8*(reg>>2)+4*hl
    f16v acc_o[4];
#pragma unroll
    for (int dt = 0; dt < 4; ++dt)
#pragma unroll
        for (int e = 0; e < 16; ++e)
            acc_o[dt][e] = 0.f;

    // ---- staging ownership (identical to R9): K/U thread->(sr,sc); V->(d0,io4)
    const int sr  = tid >> 3;          // 0..63
    const int sc  = (tid & 7) * 16;    // 0,16,...,112
    const int d0  = tid & 127;
    const int io4 = (tid >> 7) * 16;   // 0,16,32,48
    const float* kbp = Kg + kvbase + (size_t)sr * D_ + sc;
    const float* ubp = Ug + kvbase + (size_t)sr * D_ + sc;

    float4 kpre[4], upre[4];
    float  vpre[16];

    // ---- prologue: load tile 0, cvt, write into buf 0
#pragma unroll
    for (int g4 = 0; g4 < 4; ++g4) {
        kpre[g4] = *(const float4*)(kbp + g4 * 4);
        upre[g4] = *(const float4*)(ubp + g4 * 4);
    }
#pragma unroll
    for (int jj = 0; jj < 16; ++jj)
        vpre[jj] = Vg[kvbase + (size_t)(io4 + jj) * D_ + d0];
    {
        h8v kb[2], ub[2], vb[2];
        p2v* kb2 = (p2v*)kb; p2v* ub2 = (p2v*)ub; p2v* vb2 = (p2v*)vb;
#pragma unroll
        for (int g4 = 0; g4 < 4; ++g4) {
            kb2[2 * g4 + 0] = __builtin_amdgcn_cvt_pkrtz(kpre[g4].x, kpre[g4].y);
            kb2[2 * g4 + 1] = __builtin_amdgcn_cvt_pkrtz(kpre[g4].z, kpre[g4].w);
            ub2[2 * g4 + 0] = __builtin_amdgcn_cvt_pkrtz(upre[g4].x, upre[g4].y);
            ub2[2 * g4 + 1] = __builtin_amdgcn_cvt_pkrtz(upre[g4].z, upre[g4].w);
        }
#pragma unroll
        for (int jj = 0; jj < 8; ++jj)
            vb2[jj] = __builtin_amdgcn_cvt_pkrtz(vpre[2 * jj], vpre[2 * jj + 1]);
        *(h8v*)(&Ks[KIDX(sr, sc + 0)]) = kb[0];
        *(h8v*)(&Ks[KIDX(sr, sc + 8)]) = kb[1];
        *(h8v*)(&Us[KIDX(sr, sc + 0)]) = ub[0];
        *(h8v*)(&Us[KIDX(sr, sc + 8)]) = ub[1];
        *(h8v*)(&Vt[VIDX(d0, io4 + 0)]) = vb[0];
        *(h8v*)(&Vt[VIDX(d0, io4 + 8)]) = vb[1];
    }
    __syncthreads();

    for (int it = 0; it < NIT; ++it) {
        const int cur = it & 1;
        const _Float16* ksb = Ks + cur * KUSZ;
        const _Float16* usb = Us + cur * KUSZ;
        const _Float16* vtb = Vt + cur * VSZ;

        // ---- 1) issue global loads for tile t+1 (in flight across QK phase)
        const bool more = (it + 1 < NIT);
        if (more) {
            const float* kp = kbp + (size_t)(it + 1) * BN * D_;
            const float* up = ubp + (size_t)(it + 1) * BN * D_;
#pragma unroll
            for (int g4 = 0; g4 < 4; ++g4) {
                kpre[g4] = *(const float4*)(kp + g4 * 4);
                upre[g4] = *(const float4*)(up + g4 * 4);
            }
            const float* vp = Vg + kvbase + (size_t)((it + 1) * BN + io4) * D_ + d0;
#pragma unroll
            for (int jj = 0; jj < 16; ++jj)
                vpre[jj] = vp[(size_t)jj * D_];
        }

        // ---- 2) swapped QK at 32x32x16: am/an = M^T,N^T per 32-i tile; gate; pack
        // into PV B-fragments via cvt_pkrtz + permlane32_swap (no LDS round-trip).
        h8v pb[4];   // PV B-frags, one per 16-i kstep
#pragma unroll
        for (int t2 = 0; t2 < 2; ++t2) {
            f16v am, an;
#pragma unroll
            for (int e = 0; e < 16; ++e) { am[e] = 0.f; an[e] = 0.f; }
            __builtin_amdgcn_s_setprio(1);
#pragma unroll
            for (int ks = 0; ks < 8; ++ks) {
                const h8v kf = *(const h8v*)(&ksb[KIDX(t2 * 32 + l31, ks * 16 + hl * 8)]);
                const h8v uf = *(const h8v*)(&usb[KIDX(t2 * 32 + l31, ks * 16 + hl * 8)]);
                am = __builtin_amdgcn_mfma_f32_32x32x16_f16(kf, qf[ks], am, 0, 0, 0);
                an = __builtin_amdgcn_mfma_f32_32x32x16_f16(uf, qf[ks], an, 0, 0, 0);
            }
            __builtin_amdgcn_s_setprio(0);

            // gate: A = silu(M) * N  (SCALE folded into Q); reg r -> i = (r&3)+8*(r>>2)+4*hl
            int P[8];
#pragma unroll
            for (int p = 0; p < 8; ++p) {
                const float m0 = am[2 * p + 0], n0 = an[2 * p + 0];
                const float m1 = am[2 * p + 1], n1 = an[2 * p + 1];
                const float g0 = m0 * __builtin_amdgcn_rcpf(1.f + __expf(-m0)) * n0;
                const float g1 = m1 * __builtin_amdgcn_rcpf(1.f + __expf(-m1)) * n1;
                P[p] = pkf16(g0, g1);
            }
            // redistribute lane halves: B-frag wants k=i_local=(hl*8+j)
            auto sA = __builtin_amdgcn_permlane32_swap(P[0], P[2], false, false);
            auto sB = __builtin_amdgcn_permlane32_swap(P[1], P[3], false, false);
            auto sC = __builtin_amdgcn_permlane32_swap(P[4], P[6], false, false);
            auto sD = __builtin_amdgcn_permlane32_swap(P[5], P[7], false, false);
            i4v wlo = i4v{static_cast<int>(sA[0]), static_cast<int>(sB[0]),
                          static_cast<int>(sA[1]), static_cast<int>(sB[1])};
            i4v whi = i4v{static_cast<int>(sC[0]), static_cast<int>(sD[0]),
                          static_cast<int>(sC[1]), static_cast<int>(sD[1])};
            __builtin_memcpy(&pb[2 * t2 + 0], &wlo, 16);
            __builtin_memcpy(&pb[2 * t2 + 1], &whi, 16);
        }

        // ---- 3) cvt + ds_write tile t+1 into buf[cur^1] (overlaps PV below)
        if (more) {
            _Float16* ksn = Ks + (cur ^ 1) * KUSZ;
            _Float16* usn = Us + (cur ^ 1) * KUSZ;
            _Float16* vtn = Vt + (cur ^ 1) * VSZ;
            h8v kb[2], ub[2], vb[2];
            p2v* kb2 = (p2v*)kb; p2v* ub2 = (p2v*)ub; p2v* vb2 = (p2v*)vb;
#pragma unroll
            for (int g4 = 0; g4 < 4; ++g4) {
                kb2[2 * g4 + 0] = __builtin_amdgcn_cvt_pkrtz(kpre[g4].x, kpre[g4].y);
                kb2[2 * g4 + 1] = __builtin_amdgcn_cvt_pkrtz(kpre[g4].z, kpre[g4].w);
                ub2[2 * g4 + 0] = __builtin_amdgcn_cvt_pkrtz(upre[g4].x, upre[g4].y);
                ub2[2 * g4 + 1] = __builtin_amdgcn_cvt_pkrtz(upre[g4].z, upre[g4].w);
            }
#pragma unroll
            for (int jj = 0; jj < 8; ++jj)
                vb2[jj] = __builtin_amdgcn_cvt_pkrtz(vpre[2 * jj], vpre[2 * jj + 1]);
            *(h8v*)(&ksn[KIDX(sr, sc + 0)]) = kb[0];
            *(h8v*)(&ksn[KIDX(sr, sc + 8)]) = kb[1];
            *(h8v*)(&usn[KIDX(sr, sc + 0)]) = ub[0];
            *(h8v*)(&usn[KIDX(sr, sc + 8)]) = ub[1];
            *(h8v*)(&vtn[VIDX(d0, io4 + 0)]) = vb[0];
            *(h8v*)(&vtn[VIDX(d0, io4 + 8)]) = vb[1];
        }

        // ---- 4) PV at 32x32x16: O^T[dt] += Vt_frag x pb[ks2]
#pragma unroll
        for (int ks2 = 0; ks2 < 4; ++ks2) {
            h8v va[4];
#pragma unroll
            for (int dt = 0; dt < 4; ++dt)
                va[dt] = *(const h8v*)(&vtb[VIDX(dt * 32 + l31, ks2 * 16 + hl * 8)]);
            __builtin_amdgcn_s_setprio(1);
#pragma unroll
            for (int dt = 0; dt < 4; ++dt)
                acc_o[dt] = __builtin_amdgcn_mfma_f32_32x32x16_f16(va[dt], pb[ks2], acc_o[dt], 0, 0, 0);
            __builtin_amdgcn_s_setprio(0);
        }

        // ---- 5) single barrier: buf[cur^1] writes visible; buf[cur] reads done
        __syncthreads();
    }

    // ---- epilogue: lane owns one q-row; d = dt*32 + g4*8 + hl*4 + (0..3) -> float4
    {
        const int qrow = stile * BM + wave * 32 + l31;
        float* op = Og + ((size_t)(b * H_ + h) * S_ + qrow) * D_;
#pragma unroll
        for (int dt = 0; dt < 4; ++dt)
#pragma unroll
            for (int g4 = 0; g4 < 4; ++g4) {
                f4v v = f4v{acc_o[dt][4 * g4 + 0], acc_o[dt][4 * g4 + 1],
                            acc_o[dt][4 * g4 + 2], acc_o[dt][4 * g4 + 3]};
                *(f4v*)(op + dt * 32 + g4 * 8 + hl * 4) = v;
            }
    }
}

extern "C" void kernel_launch(void* const* d_in, const int* in_sizes, int n_in,
                              void* d_out, int out_size, void* d_ws, size_t ws_size,
                              hipStream_t stream) {
    const float* Q = (const float*)d_in[0];
    const float* K = (const float*)d_in[1];
    const float* U = (const float*)d_in[2];
    const float* V = (const float*)d_in[3];
    float* out = (float*)d_out;

    const int grid = (S_ / BM) * B_ * H_;   // 8 * 32 = 256 blocks, 1/CU
    flashmlp_kernel<<<dim3(grid), dim3(TPB), 0, stream>>>(Q, K, U, V, out);
}

// Round 13
// 195.551 us; speedup vs baseline: 1.7435x; 1.0241x over previous
//
#include <hip/hip_runtime.h>

#define B_   2
#define H_   16
#define G_   4
#define S_   2048
#define D_   128
#define I_   2048

#define BM   256
#define BN   64
#define TPB  512   // 8 waves x 32 q-rows
#define NIT  (I_ / BN)   // 32
#define TSZ  8192        // one tile: 16 KB = 8192 f16 (K/U: 64x128, Vt: 128x64)

// T2 XOR-swizzle on 8-elem (16B) granules by row&7. The ws image is PRE-swizzled by
// the convert kernel, so LDS holds the same image and reads use these macros.
#define KIDX(r,c) ((r)*128 + ((c) ^ (((r)&7)<<3)))   // Ks/Us: [64][128] f16
#define VIDX(d,c) ((d)*64  + ((c) ^ (((d)&7)<<3)))   // Vt:    [128][64] f16

static constexpr float SCALE = 0.08838834764831845f;  // 1/sqrt(128)

typedef __fp16   p2v  __attribute__((ext_vector_type(2)));
typedef _Float16 h8v  __attribute__((ext_vector_type(8)));
typedef float    f4v  __attribute__((ext_vector_type(4)));
typedef float    f16v __attribute__((ext_vector_type(16)));
typedef int      i4v  __attribute__((ext_vector_type(4)));

__device__ __forceinline__ int pkf16(float a, float b) {
    p2v t = __builtin_amdgcn_cvt_pkrtz(a, b);
    int r; __builtin_memcpy(&r, &t, 4); return r;
}

// async global->LDS, 16 B per lane; LDS dest = wave-uniform base + lane*16
#define GL_LDS(gp, lp) __builtin_amdgcn_global_load_lds(                      \
    (const __attribute__((address_space(1))) void*)(gp),                      \
    (__attribute__((address_space(3))) void*)(lp), 16, 0, 0)

// ---------------- pre-pass: K/U/V f32 -> f16 tiles, transposed (V) + pre-swizzled
// ws layout: [kh][m][it][8192 f16], m: 0=K, 1=U, 2=Vt
__global__ __launch_bounds__(256) void convert_kernel(
    const float* __restrict__ Kg, const float* __restrict__ Ug,
    const float* __restrict__ Vg, _Float16* __restrict__ ws)
{
    const int bid = blockIdx.x;
    const int tid = threadIdx.x;
    __shared__ float vt[64 * 128];
    if (bid < 256) {
        // K/U tile: image[r*128+cc] = src[it*64+r][cc ^ ((r&7)<<3)]
        const int kh = bid >> 6, m = (bid >> 5) & 1, it = bid & 31;
        const float* src = (m ? Ug : Kg) + (size_t)kh * I_ * D_ + (size_t)it * BN * D_;
        _Float16* dst = ws + (((size_t)kh * 3 + m) * 32 + it) * TSZ;
        const int r   = tid >> 2;
        const int cb  = (tid & 3) * 32;
        const int swz = (r & 7) << 3;
#pragma unroll
        for (int g = 0; g < 4; ++g) {
            const int cc0 = cb + g * 8;
            const int d0  = cc0 ^ swz;
            const float4 a = *(const float4*)(src + r * D_ + d0);
            const float4 c = *(const float4*)(src + r * D_ + d0 + 4);
            h8v v; p2v* v2 = (p2v*)&v;
            v2[0] = __builtin_amdgcn_cvt_pkrtz(a.x, a.y);
            v2[1] = __builtin_amdgcn_cvt_pkrtz(a.z, a.w);
            v2[2] = __builtin_amdgcn_cvt_pkrtz(c.x, c.y);
            v2[3] = __builtin_amdgcn_cvt_pkrtz(c.z, c.w);
            *(h8v*)(dst + r * 128 + cc0) = v;
        }
    } else {
        // Vt tile: image[d*64+cc] = V[it*64 + (cc ^ ((d&7)<<3))][d], via LDS transpose
        const int v  = bid - 256;
        const int kh = v >> 5, it = v & 31;
        const float* src = Vg + (size_t)kh * I_ * D_ + (size_t)it * BN * D_;
#pragma unroll
        for (int p = 0; p < 8; ++p) {
            const int idx = p * 256 + tid;
            const int i   = idx >> 5;
            const int d4  = (idx & 31) * 4;
            *(float4*)(&vt[i * 128 + d4]) = *(const float4*)(src + (size_t)i * D_ + d4);
        }
        __syncthreads();
        _Float16* dst = ws + (((size_t)kh * 3 + 2) * 32 + it) * TSZ;
        const int d   = tid >> 1;
        const int cb  = (tid & 1) * 32;
        const int swz = (d & 7) << 3;
#pragma unroll
        for (int g = 0; g < 4; ++g) {
            const int cc0 = cb + g * 8;
            const int ib  = cc0 ^ swz;   // 8 consecutive i
            h8v w; p2v* w2 = (p2v*)&w;
#pragma unroll
            for (int pr = 0; pr < 4; ++pr)
                w2[pr] = __builtin_amdgcn_cvt_pkrtz(vt[(ib + 2 * pr) * 128 + d],
                                                    vt[(ib + 2 * pr + 1) * 128 + d]);
            *(h8v*)(dst + d * 64 + cc0) = w;
        }
    }
}

// ---------------- main kernel
__global__ __launch_bounds__(TPB, 2) void flashmlp_kernel(
    const float* __restrict__ Qg, const _Float16* __restrict__ ws,
    float* __restrict__ Og)
{
    // LDS: dbuf K/U/V = 6 x 16 KB = 96 KB (1 block/CU)
    __shared__ _Float16 Ks[2 * TSZ];
    __shared__ _Float16 Us[2 * TSZ];
    __shared__ _Float16 Vt[2 * TSZ];

    // ---- block decode with XCD swizzle: xcd = bid&7 -> kv-head = xcd>>1
    const int bid   = blockIdx.x;
    const int xcd   = bid & 7;
    const int kh    = xcd >> 1;
    const int j     = ((bid >> 3) << 1) | (xcd & 1);   // 0..63 within head
    const int stile = j & 7;
    const int bg    = j >> 3;
    const int b     = bg >> 2;
    const int g     = bg & 3;
    const int h     = kh * G_ + g;

    const int tid  = threadIdx.x;
    const int wave = tid >> 6;         // 0..7
    const int lane = tid & 63;
    const int l31  = lane & 31;
    const int hl   = lane >> 5;

    const size_t qbase = ((size_t)(b * H_ + h) * S_ + (size_t)stile * BM) * D_;
    const _Float16* wsK = ws + (size_t)kh * 3 * 32 * TSZ;            // K tiles
    const _Float16* wsU = wsK + (size_t)32 * TSZ;                    // U tiles
    const _Float16* wsV = wsK + (size_t)64 * TSZ;                    // Vt tiles

    // per-lane source elem offset within a tile (wave covers 2 KB; 2 calls of 1 KB)
    const int so = wave * 1024 + lane * 8;
    const int su = wave * 1024;        // wave-uniform LDS elem offset

    // ---- Q fragments as the 32x32x16 B-operand (SCALE folded in)
    h8v qf[8];
    {
        const float* qp = Qg + qbase + (size_t)(wave * 32 + l31) * D_;
#pragma unroll
        for (int ks = 0; ks < 8; ++ks) {
            const float4 a = *(const float4*)(qp + ks * 16 + hl * 8);
            const float4 c = *(const float4*)(qp + ks * 16 + hl * 8 + 4);
            h8v v; p2v* v2 = (p2v*)&v;
            v2[0] = __builtin_amdgcn_cvt_pkrtz(a.x * SCALE, a.y * SCALE);
            v2[1] = __builtin_amdgcn_cvt_pkrtz(a.z * SCALE, a.w * SCALE);
            v2[2] = __builtin_amdgcn_cvt_pkrtz(c.x * SCALE, c.y * SCALE);
            v2[3] = __builtin_amdgcn_cvt_pkrtz(c.z * SCALE, c.w * SCALE);
            qf[ks] = v;
        }
    }

    // acc_o[dt]: O^T (32d x 32q); lane col q=l31, row d = dt*32+(reg&3)+8*(reg>>2)+4*hl
    f16v acc_o[4];
#pragma unroll
    for (int dt = 0; dt < 4; ++dt)
#pragma unroll
        for (int e = 0; e < 16; ++e)
            acc_o[dt][e] = 0.f;

    // ---- prologue: DMA tile 0 into buf 0 (syncthreads drains vmcnt)
    {
        const _Float16* kt = wsK;
        const _Float16* ut = wsU;
        const _Float16* vt = wsV;
        GL_LDS(kt + so,       Ks + su);
        GL_LDS(kt + so + 512, Ks + su + 512);
        GL_LDS(ut + so,       Us + su);
        GL_LDS(ut + so + 512, Us + su + 512);
        GL_LDS(vt + so,       Vt + su);
        GL_LDS(vt + so + 512, Vt + su + 512);
    }
    __syncthreads();

    for (int it = 0; it < NIT; ++it) {
        const int cur = it & 1;
        const _Float16* ksb = Ks + cur * TSZ;
        const _Float16* usb = Us + cur * TSZ;
        const _Float16* vtb = Vt + cur * TSZ;

        // ---- 1) DMA tile t+1 into buf[cur^1]; completes by the end-of-iter barrier
        if (it + 1 < NIT) {
            const int nb = (cur ^ 1) * TSZ;
            const _Float16* kt = wsK + (size_t)(it + 1) * TSZ;
            const _Float16* ut = wsU + (size_t)(it + 1) * TSZ;
            const _Float16* vt = wsV + (size_t)(it + 1) * TSZ;
            GL_LDS(kt + so,       Ks + nb + su);
            GL_LDS(kt + so + 512, Ks + nb + su + 512);
            GL_LDS(ut + so,       Us + nb + su);
            GL_LDS(ut + so + 512, Us + nb + su + 512);
            GL_LDS(vt + so,       Vt + nb + su);
            GL_LDS(vt + so + 512, Vt + nb + su + 512);
        }

        // ---- 2) per 32-i half: swapped QK (32x32x16), gate+pack in-register,
        // then PV for that half (overlaps next half's QK LDS reads)
#pragma unroll
        for (int t2 = 0; t2 < 2; ++t2) {
            f16v am, an;
#pragma unroll
            for (int e = 0; e < 16; ++e) { am[e] = 0.f; an[e] = 0.f; }
            __builtin_amdgcn_s_setprio(1);
#pragma unroll
            for (int ks = 0; ks < 8; ++ks) {
                const h8v kf = *(const h8v*)(&ksb[KIDX(t2 * 32 + l31, ks * 16 + hl * 8)]);
                const h8v uf = *(const h8v*)(&usb[KIDX(t2 * 32 + l31, ks * 16 + hl * 8)]);
                am = __builtin_amdgcn_mfma_f32_32x32x16_f16(kf, qf[ks], am, 0, 0, 0);
                an = __builtin_amdgcn_mfma_f32_32x32x16_f16(uf, qf[ks], an, 0, 0, 0);
            }
            __builtin_amdgcn_s_setprio(0);

            // gate: A = silu(M) * N; reg r -> i = (r&3)+8*(r>>2)+4*hl
            int P[8];
#pragma unroll
            for (int p = 0; p < 8; ++p) {
                const float m0 = am[2 * p + 0], n0 = an[2 * p + 0];
                const float m1 = am[2 * p + 1], n1 = an[2 * p + 1];
                const float g0 = m0 * __builtin_amdgcn_rcpf(1.f + __expf(-m0)) * n0;
                const float g1 = m1 * __builtin_amdgcn_rcpf(1.f + __expf(-m1)) * n1;
                P[p] = pkf16(g0, g1);
            }
            // redistribute lane halves -> PV B-frags (k = hl*8+j)
            auto sA = __builtin_amdgcn_permlane32_swap(P[0], P[2], false, false);
            auto sB = __builtin_amdgcn_permlane32_swap(P[1], P[3], false, false);
            auto sC = __builtin_amdgcn_permlane32_swap(P[4], P[6], false, false);
            auto sD = __builtin_amdgcn_permlane32_swap(P[5], P[7], false, false);
            h8v pb0, pb1;
            {
                i4v wlo = i4v{static_cast<int>(sA[0]), static_cast<int>(sB[0]),
                              static_cast<int>(sA[1]), static_cast<int>(sB[1])};
                i4v whi = i4v{static_cast<int>(sC[0]), static_cast<int>(sD[0]),
                              static_cast<int>(sC[1]), static_cast<int>(sD[1])};
                __builtin_memcpy(&pb0, &wlo, 16);
                __builtin_memcpy(&pb1, &whi, 16);
            }

            // PV for this 32-i half: ks2 = t2*2 + {0,1}
#pragma unroll
            for (int k2 = 0; k2 < 2; ++k2) {
                const int ks2 = t2 * 2 + k2;
                const h8v pb = k2 ? pb1 : pb0;
                h8v va[4];
#pragma unroll
                for (int dt = 0; dt < 4; ++dt)
                    va[dt] = *(const h8v*)(&vtb[VIDX(dt * 32 + l31, ks2 * 16 + hl * 8)]);
                __builtin_amdgcn_s_setprio(1);
#pragma unroll
                for (int dt = 0; dt < 4; ++dt)
                    acc_o[dt] = __builtin_amdgcn_mfma_f32_32x32x16_f16(va[dt], pb, acc_o[dt], 0, 0, 0);
                __builtin_amdgcn_s_setprio(0);
            }
        }

        // ---- 3) single barrier: DMA drained (vmcnt) + buf[cur] reads done
        __syncthreads();
    }

    // ---- epilogue: lane owns one q-row; d = dt*32 + g4*8 + hl*4 + (0..3)
    {
        const int qrow = stile * BM + wave * 32 + l31;
        float* op = Og + ((size_t)(b * H_ + h) * S_ + qrow) * D_;
#pragma unroll
        for (int dt = 0; dt < 4; ++dt)
#pragma unroll
            for (int g4 = 0; g4 < 4; ++g4) {
                f4v v = f4v{acc_o[dt][4 * g4 + 0], acc_o[dt][4 * g4 + 1],
                            acc_o[dt][4 * g4 + 2], acc_o[dt][4 * g4 + 3]};
                *(f4v*)(op + dt * 32 + g4 * 8 + hl * 4) = v;
            }
    }
}

extern "C" void kernel_launch(void* const* d_in, const int* in_sizes, int n_in,
                              void* d_out, int out_size, void* d_ws, size_t ws_size,
                              hipStream_t stream) {
    const float* Q = (const float*)d_in[0];
    const float* K = (const float*)d_in[1];
    const float* U = (const float*)d_in[2];
    const float* V = (const float*)d_in[3];
    float* out = (float*)d_out;
    _Float16* ws = (_Float16*)d_ws;   // needs 4*3*32*16384 B = 6.3 MB

    convert_kernel<<<dim3(384), dim3(256), 0, stream>>>(K, U, V, ws);
    flashmlp_kernel<<<dim3((S_ / BM) * B_ * H_), dim3(TPB), 0, stream>>>(Q, ws, out);
}